// Round 1
// baseline (78.989 us; speedup 1.0000x reference)
//
#include <hip/hip_runtime.h>
#include <hip/hip_bf16.h>

#define T_ 4096
#define D_ 512
#define H_ 8
#define BAND 16

typedef float f32x4 __attribute__((ext_vector_type(4)));
typedef __bf16 bf16x8 __attribute__((ext_vector_type(8)));
typedef unsigned short us8 __attribute__((ext_vector_type(8)));
typedef unsigned short us4 __attribute__((ext_vector_type(4)));

__device__ __forceinline__ unsigned short f2b(float f) {
  union { float f; unsigned u; } v; v.f = f;
  unsigned r = v.u + 0x7fffu + ((v.u >> 16) & 1u);
  return (unsigned short)(r >> 16);
}

__device__ __forceinline__ f32x4 mfma16(bf16x8 a, bf16x8 b, f32x4 c) {
  return __builtin_amdgcn_mfma_f32_16x16x32_bf16(a, b, c, 0, 0, 0);
}

#define GLD16(gp, lp) __builtin_amdgcn_global_load_lds( \
    (const __attribute__((address_space(1))) void*)(gp), \
    (__attribute__((address_space(3))) void*)(lp), 16, 0, 0)

// ---------------- weight fp32 -> bf16 ----------------
__global__ __launch_bounds__(256) void cvt_w_k(const float* __restrict__ win,
                                               const float* __restrict__ wout,
                                               unsigned short* __restrict__ winb,
                                               unsigned short* __restrict__ woutb) {
  int i = blockIdx.x * 256 + threadIdx.x;
  const int n1 = 3 * D_ * D_ / 4;  // 196608 float4s of w_in
  if (i < n1) {
    float4 v = ((const float4*)win)[i];
    us4 o; o.x = f2b(v.x); o.y = f2b(v.y); o.z = f2b(v.z); o.w = f2b(v.w);
    ((us4*)winb)[i] = o;
  } else {
    int j = i - n1;  // grid sized exactly: j < 65536
    float4 v = ((const float4*)wout)[j];
    us4 o; o.x = f2b(v.x); o.y = f2b(v.y); o.z = f2b(v.z); o.w = f2b(v.w);
    ((us4*)woutb)[j] = o;
  }
}

// ---------------- LayerNorm -> bf16 h ----------------
__global__ __launch_bounds__(256) void ln_k(const float* __restrict__ x,
                                            const float* __restrict__ g,
                                            const float* __restrict__ bt,
                                            unsigned short* __restrict__ h) {
  int wave = threadIdx.x >> 6, lane = threadIdx.x & 63;
  size_t row = (size_t)blockIdx.x * 4 + wave;
  const float4* xr = (const float4*)(x + row * D_);
  float4 a = xr[lane * 2], b = xr[lane * 2 + 1];
  float s = a.x + a.y + a.z + a.w + b.x + b.y + b.z + b.w;
  #pragma unroll
  for (int o = 32; o; o >>= 1) s += __shfl_xor(s, o, 64);
  float mu = s * (1.0f / D_);
  float d0 = a.x - mu, d1 = a.y - mu, d2 = a.z - mu, d3 = a.w - mu;
  float d4 = b.x - mu, d5 = b.y - mu, d6 = b.z - mu, d7 = b.w - mu;
  float q = d0*d0 + d1*d1 + d2*d2 + d3*d3 + d4*d4 + d5*d5 + d6*d6 + d7*d7;
  #pragma unroll
  for (int o = 32; o; o >>= 1) q += __shfl_xor(q, o, 64);
  float rstd = rsqrtf(q * (1.0f / D_) + 1e-5f);
  const float4* gr = (const float4*)g;
  const float4* br = (const float4*)bt;
  float4 g0 = gr[lane * 2], g1 = gr[lane * 2 + 1];
  float4 b0 = br[lane * 2], b1 = br[lane * 2 + 1];
  us8 o8;
  o8[0] = f2b(d0 * rstd * g0.x + b0.x);
  o8[1] = f2b(d1 * rstd * g0.y + b0.y);
  o8[2] = f2b(d2 * rstd * g0.z + b0.z);
  o8[3] = f2b(d3 * rstd * g0.w + b0.w);
  o8[4] = f2b(d4 * rstd * g1.x + b1.x);
  o8[5] = f2b(d5 * rstd * g1.y + b1.y);
  o8[6] = f2b(d6 * rstd * g1.z + b1.z);
  o8[7] = f2b(d7 * rstd * g1.w + b1.w);
  *((us8*)(h + row * D_) + lane) = o8;
}

// ---------------- GEMM C = A @ Bw^T (+bias, optional +x residual) ----------------
// A: [M][K] bf16, Bw: [N][K] bf16. 128x128 tile, BK=32, 4 waves (2x2), 4x4 frags.
template <bool FINAL>
__global__ __launch_bounds__(256) void gemm_bt(const unsigned short* __restrict__ A,
                                               const unsigned short* __restrict__ Bw,
                                               const float* __restrict__ bias,
                                               const float* __restrict__ xres,
                                               unsigned short* __restrict__ obf,
                                               float* __restrict__ ofp,
                                               int N, int K) {
  __shared__ unsigned short As[128 * 32];
  __shared__ unsigned short Bs[128 * 32];
  int tid = threadIdx.x;
  int lane = tid & 63;
  int wave = tid >> 6;
  int wm = wave >> 1, wn = wave & 1;
  int fr = lane & 15, fq = lane >> 4;
  int bm = blockIdx.x, bn = blockIdx.y;

  int off0 = tid * 16;        // byte offset into 8KB tile
  int off1 = off0 + 4096;
  int rA0 = off0 >> 6, cE0 = (off0 & 63) >> 1;
  int rA1 = off1 >> 6, cE1 = (off1 & 63) >> 1;
  const unsigned short* Ag0 = A + (size_t)(bm * 128 + rA0) * K + cE0;
  const unsigned short* Ag1 = A + (size_t)(bm * 128 + rA1) * K + cE1;
  const unsigned short* Bg0 = Bw + (size_t)(bn * 128 + rA0) * K + cE0;
  const unsigned short* Bg1 = Bw + (size_t)(bn * 128 + rA1) * K + cE1;

  f32x4 acc[4][4] = {};

  int nk = K >> 5;
  for (int kt = 0; kt < nk; ++kt) {
    int ko = kt * 32;
    GLD16(Ag0 + ko, (char*)As + off0);
    GLD16(Ag1 + ko, (char*)As + off1);
    GLD16(Bg0 + ko, (char*)Bs + off0);
    GLD16(Bg1 + ko, (char*)Bs + off1);
    __syncthreads();
    bf16x8 af[4], bfr[4];
    #pragma unroll
    for (int i = 0; i < 4; ++i)
      af[i] = *(const bf16x8*)(As + (wm * 64 + i * 16 + fr) * 32 + fq * 8);
    #pragma unroll
    for (int i = 0; i < 4; ++i)
      bfr[i] = *(const bf16x8*)(Bs + (wn * 64 + i * 16 + fr) * 32 + fq * 8);
    #pragma unroll
    for (int i = 0; i < 4; ++i)
      #pragma unroll
      for (int j = 0; j < 4; ++j)
        acc[i][j] = mfma16(af[i], bfr[j], acc[i][j]);
    __syncthreads();
  }

  int rbase = bm * 128 + wm * 64 + fq * 4;
  int cb = bn * 128 + wn * 64 + fr;
  #pragma unroll
  for (int j = 0; j < 4; ++j) {
    int col = cb + j * 16;
    float bv = bias[col];
    #pragma unroll
    for (int i = 0; i < 4; ++i) {
      #pragma unroll
      for (int r = 0; r < 4; ++r) {
        size_t idx = (size_t)(rbase + i * 16 + r) * N + col;
        float v = acc[i][j][r] + bv;
        if (FINAL) ofp[idx] = xres[idx] + v;
        else       obf[idx] = f2b(v);
      }
    }
  }
}

// ---------------- banded attention ----------------
// grid (T/64, H, B), 256 threads. Per block: 64 q-rows of one (b,h),
// K/V rows t0-16 .. t0+79 (96 rows), dh=64.
__global__ __launch_bounds__(256) void attn_k(const unsigned short* __restrict__ qkv,
                                              unsigned short* __restrict__ obuf) {
  __shared__ unsigned short Ks[96 * 72];    // K rows, row-major, padded
  __shared__ unsigned short Vt[64 * 112];   // V transposed [d][r], padded
  __shared__ unsigned short Ps[64 * 104];   // P [t_local][r], padded
  int tid = threadIdx.x;
  int lane = tid & 63, wave = tid >> 6;
  int fr = lane & 15, fq = lane >> 4;
  int t0 = blockIdx.x * 64;
  int hh = blockIdx.y;
  int bb = blockIdx.z;
  size_t rowbase = (size_t)bb * T_;

  // stage K (row-major) and V (transposed)
  #pragma unroll
  for (int it = 0; it < 3; ++it) {
    int c = tid + it * 256;       // 0..767
    int r = c % 96;
    int d8 = (c / 96) * 8;
    int tg = t0 - BAND + r;
    us8 kv = {0,0,0,0,0,0,0,0}, vv = {0,0,0,0,0,0,0,0};
    if (tg >= 0 && tg < T_) {
      const unsigned short* p = qkv + (rowbase + tg) * 1536 + hh * 64 + d8;
      kv = *(const us8*)(p + 512);
      vv = *(const us8*)(p + 1024);
    }
    *(us8*)(Ks + r * 72 + d8) = kv;
    #pragma unroll
    for (int j = 0; j < 8; ++j) Vt[(d8 + j) * 112 + r] = vv[j];
  }

  // Q fragments straight from global (A-frag: row=fr, k=8*fq)
  bf16x8 qf0, qf1;
  {
    int tq = t0 + wave * 16 + fr;
    const unsigned short* qp = qkv + (rowbase + tq) * 1536 + hh * 64 + fq * 8;
    qf0 = *(const bf16x8*)qp;
    qf1 = *(const bf16x8*)(qp + 32);
  }
  __syncthreads();

  // S = Q K^T  (per wave: 16 rows x 96 cols)
  f32x4 sa[6];
  #pragma unroll
  for (int c = 0; c < 6; ++c) sa[c] = (f32x4){0.f, 0.f, 0.f, 0.f};
  #pragma unroll
  for (int c = 0; c < 6; ++c) {
    bf16x8 k0 = *(const bf16x8*)(Ks + (c * 16 + fr) * 72 + fq * 8);
    bf16x8 k1 = *(const bf16x8*)(Ks + (c * 16 + fr) * 72 + 32 + fq * 8);
    sa[c] = mfma16(qf0, k0, sa[c]);
    sa[c] = mfma16(qf1, k1, sa[c]);
  }

  // banded mask + row softmax (rows live on 16-lane groups)
  float inv[4];
  float pvv[6][4];
  #pragma unroll
  for (int r = 0; r < 4; ++r) {
    int tg = t0 + wave * 16 + fq * 4 + r;
    float m = -1e30f;
    #pragma unroll
    for (int c = 0; c < 6; ++c) {
      int cg = t0 - BAND + c * 16 + fr;
      bool ok = (cg >= tg - BAND) && (cg <= tg + BAND) && (cg >= 0) && (cg < T_);
      float v = ok ? sa[c][r] * 0.125f : -1e30f;
      pvv[c][r] = v;
      m = fmaxf(m, v);
    }
    #pragma unroll
    for (int o = 8; o; o >>= 1) m = fmaxf(m, __shfl_xor(m, o, 64));
    float s = 0.0f;
    #pragma unroll
    for (int c = 0; c < 6; ++c) {
      float e = exp2f((pvv[c][r] - m) * 1.44269504f);
      pvv[c][r] = e;
      s += e;
    }
    #pragma unroll
    for (int o = 8; o; o >>= 1) s += __shfl_xor(s, o, 64);
    inv[r] = 1.0f / s;
  }

  // P -> LDS (bf16) for PV A-frags
  #pragma unroll
  for (int c = 0; c < 6; ++c)
    #pragma unroll
    for (int r = 0; r < 4; ++r)
      Ps[(wave * 16 + fq * 4 + r) * 104 + c * 16 + fr] = f2b(pvv[c][r]);

  __syncthreads();

  // O = P V   (B^T-form with Bst = Vt[d][r])
  f32x4 oa[4];
  #pragma unroll
  for (int c2 = 0; c2 < 4; ++c2) oa[c2] = (f32x4){0.f, 0.f, 0.f, 0.f};
  #pragma unroll
  for (int kk = 0; kk < 3; ++kk) {
    bf16x8 pa = *(const bf16x8*)(Ps + (wave * 16 + fr) * 104 + kk * 32 + fq * 8);
    #pragma unroll
    for (int c2 = 0; c2 < 4; ++c2) {
      bf16x8 vb = *(const bf16x8*)(Vt + (c2 * 16 + fr) * 112 + kk * 32 + fq * 8);
      oa[c2] = mfma16(pa, vb, oa[c2]);
    }
  }

  size_t orow = rowbase + t0 + wave * 16 + fq * 4;
  #pragma unroll
  for (int c2 = 0; c2 < 4; ++c2)
    #pragma unroll
    for (int r = 0; r < 4; ++r)
      obuf[(orow + r) * D_ + hh * 64 + c2 * 16 + fr] = f2b(oa[c2][r] * inv[r]);
}

extern "C" void kernel_launch(void* const* d_in, const int* in_sizes, int n_in,
                              void* d_out, int out_size, void* d_ws, size_t ws_size,
                              hipStream_t stream) {
  (void)in_sizes; (void)n_in; (void)out_size; (void)ws_size;
  const float* x     = (const float*)d_in[0];
  const float* ln_g  = (const float*)d_in[1];
  const float* ln_b  = (const float*)d_in[2];
  const float* w_in  = (const float*)d_in[3];
  const float* b_in  = (const float*)d_in[4];
  const float* w_out = (const float*)d_in[5];
  const float* b_out = (const float*)d_in[6];
  float* out = (float*)d_out;

  char* ws = (char*)d_ws;
  unsigned short* hb    = (unsigned short*)(ws);              // 8192*512   bf16  (8 MB)
  unsigned short* winb  = (unsigned short*)(ws + 8388608);    // 1536*512   bf16
  unsigned short* woutb = (unsigned short*)(ws + 9961472);    // 512*512    bf16
  unsigned short* qkvb  = (unsigned short*)(ws + 10485760);   // 8192*1536  bf16  (24 MB)
  unsigned short* obf   = (unsigned short*)(ws + 35651584);   // 8192*512   bf16  (8 MB)

  cvt_w_k<<<1024, 256, 0, stream>>>(w_in, w_out, winb, woutb);
  ln_k<<<2048, 256, 0, stream>>>(x, ln_g, ln_b, hb);
  gemm_bt<false><<<dim3(64, 12), 256, 0, stream>>>(hb, winb, b_in, nullptr, qkvb, nullptr, 1536, 512);
  attn_k<<<dim3(64, 8, 2), 256, 0, stream>>>(qkvb, obf);
  gemm_bt<true><<<dim3(64, 4), 256, 0, stream>>>(obf, woutb, b_out, x, nullptr, out, 512, 512);
}

// Round 2
// 66.419 us; speedup vs baseline: 1.1893x; 1.1893x over previous
//
#include <hip/hip_runtime.h>
#include <hip/hip_bf16.h>

#define T_ 4096
#define D_ 512
#define H_ 8
#define BAND 16

typedef float f32x4 __attribute__((ext_vector_type(4)));
typedef __bf16 bf16x8 __attribute__((ext_vector_type(8)));
typedef unsigned short us8 __attribute__((ext_vector_type(8)));
typedef unsigned short us4 __attribute__((ext_vector_type(4)));

__device__ __forceinline__ unsigned short f2b(float f) {
  union { float f; unsigned u; } v; v.f = f;
  unsigned r = v.u + 0x7fffu + ((v.u >> 16) & 1u);
  return (unsigned short)(r >> 16);
}

__device__ __forceinline__ f32x4 mfma16(bf16x8 a, bf16x8 b, f32x4 c) {
  return __builtin_amdgcn_mfma_f32_16x16x32_bf16(a, b, c, 0, 0, 0);
}

#define GLD16(gp, lp) __builtin_amdgcn_global_load_lds( \
    (const __attribute__((address_space(1))) void*)(gp), \
    (__attribute__((address_space(3))) void*)(lp), 16, 0, 0)

// ---------------- fused: weight fp32->bf16 cvt + LayerNorm ----------------
// blocks [0,2048): LN (4 rows each). blocks [2048,3072): weight cvt.
__global__ __launch_bounds__(256) void prep_k(const float* __restrict__ x,
                                              const float* __restrict__ g,
                                              const float* __restrict__ bt,
                                              const float* __restrict__ win,
                                              const float* __restrict__ wout,
                                              unsigned short* __restrict__ h,
                                              unsigned short* __restrict__ winb,
                                              unsigned short* __restrict__ woutb) {
  int bx = blockIdx.x;
  if (bx >= 2048) {
    int i = (bx - 2048) * 256 + threadIdx.x;
    const int n1 = 3 * D_ * D_ / 4;  // 196608 float4s of w_in
    if (i < n1) {
      float4 v = ((const float4*)win)[i];
      us4 o; o.x = f2b(v.x); o.y = f2b(v.y); o.z = f2b(v.z); o.w = f2b(v.w);
      ((us4*)winb)[i] = o;
    } else {
      int j = i - n1;  // j < 65536
      float4 v = ((const float4*)wout)[j];
      us4 o; o.x = f2b(v.x); o.y = f2b(v.y); o.z = f2b(v.z); o.w = f2b(v.w);
      ((us4*)woutb)[j] = o;
    }
    return;
  }
  int wave = threadIdx.x >> 6, lane = threadIdx.x & 63;
  size_t row = (size_t)bx * 4 + wave;
  const float4* xr = (const float4*)(x + row * D_);
  float4 a = xr[lane * 2], b = xr[lane * 2 + 1];
  float s = a.x + a.y + a.z + a.w + b.x + b.y + b.z + b.w;
  #pragma unroll
  for (int o = 32; o; o >>= 1) s += __shfl_xor(s, o, 64);
  float mu = s * (1.0f / D_);
  float d0 = a.x - mu, d1 = a.y - mu, d2 = a.z - mu, d3 = a.w - mu;
  float d4 = b.x - mu, d5 = b.y - mu, d6 = b.z - mu, d7 = b.w - mu;
  float q = d0*d0 + d1*d1 + d2*d2 + d3*d3 + d4*d4 + d5*d5 + d6*d6 + d7*d7;
  #pragma unroll
  for (int o = 32; o; o >>= 1) q += __shfl_xor(q, o, 64);
  float rstd = rsqrtf(q * (1.0f / D_) + 1e-5f);
  const float4* gr = (const float4*)g;
  const float4* br = (const float4*)bt;
  float4 g0 = gr[lane * 2], g1 = gr[lane * 2 + 1];
  float4 b0 = br[lane * 2], b1 = br[lane * 2 + 1];
  us8 o8;
  o8[0] = f2b(d0 * rstd * g0.x + b0.x);
  o8[1] = f2b(d1 * rstd * g0.y + b0.y);
  o8[2] = f2b(d2 * rstd * g0.z + b0.z);
  o8[3] = f2b(d3 * rstd * g0.w + b0.w);
  o8[4] = f2b(d4 * rstd * g1.x + b1.x);
  o8[5] = f2b(d5 * rstd * g1.y + b1.y);
  o8[6] = f2b(d6 * rstd * g1.z + b1.z);
  o8[7] = f2b(d7 * rstd * g1.w + b1.w);
  *((us8*)(h + row * D_) + lane) = o8;
}

// ---------------- GEMM C = A @ Bw^T (+bias, optional +x residual) ----------------
// A: [M][K] bf16, Bw: [N][K] bf16. 128x128 tile, BK=64, 4 waves (2x2), 4x4 frags.
// LDS layout: row stride 64 elems (128B); 16B unit u holds global k-unit (u ^ (row&7))
// -> global_load_lds source stays row-coalesced, ds_read_b128 is conflict-optimal.
template <bool FINAL>
__global__ __launch_bounds__(256) void gemm_bt(const unsigned short* __restrict__ A,
                                               const unsigned short* __restrict__ Bw,
                                               const float* __restrict__ bias,
                                               const float* __restrict__ xres,
                                               unsigned short* __restrict__ obf,
                                               float* __restrict__ ofp,
                                               int N, int K) {
  __shared__ unsigned short As[128 * 64];
  __shared__ unsigned short Bs[128 * 64];
  int tid = threadIdx.x;
  int lane = tid & 63;
  int wave = tid >> 6;
  int wm = wave >> 1, wn = wave & 1;
  int fr = lane & 15, fq = lane >> 4;
  int bm = blockIdx.x, bn = blockIdx.y;

  const unsigned short* Ap[4];
  const unsigned short* Bp[4];
  int loff[4];
  #pragma unroll
  for (int g = 0; g < 4; ++g) {
    int s = g * 256 + tid;          // 16B-unit index, 0..1023
    int row = s >> 3, u = s & 7;
    int uu = u ^ (row & 7);         // pre-swizzled global k-unit
    Ap[g] = A + (size_t)(bm * 128 + row) * K + uu * 8;
    Bp[g] = Bw + (size_t)(bn * 128 + row) * K + uu * 8;
    loff[g] = s * 16;
  }

  f32x4 acc[4][4] = {};

  int nk = K >> 6;
  for (int kt = 0; kt < nk; ++kt) {
    int ko = kt * 64;
    #pragma unroll
    for (int g = 0; g < 4; ++g) GLD16(Ap[g] + ko, (char*)As + loff[g]);
    #pragma unroll
    for (int g = 0; g < 4; ++g) GLD16(Bp[g] + ko, (char*)Bs + loff[g]);
    __syncthreads();
    #pragma unroll
    for (int kk = 0; kk < 2; ++kk) {
      bf16x8 af[4], bfr[4];
      #pragma unroll
      for (int i = 0; i < 4; ++i) {
        int row = wm * 64 + i * 16 + fr;
        af[i] = *(const bf16x8*)(As + row * 64 + (((kk * 4 + fq) ^ (fr & 7)) << 3));
      }
      #pragma unroll
      for (int j = 0; j < 4; ++j) {
        int row = wn * 64 + j * 16 + fr;
        bfr[j] = *(const bf16x8*)(Bs + row * 64 + (((kk * 4 + fq) ^ (fr & 7)) << 3));
      }
      #pragma unroll
      for (int i = 0; i < 4; ++i)
        #pragma unroll
        for (int j = 0; j < 4; ++j)
          acc[i][j] = mfma16(af[i], bfr[j], acc[i][j]);
    }
    __syncthreads();
  }

  int rbase = bm * 128 + wm * 64 + fq * 4;
  int cb = bn * 128 + wn * 64 + fr;
  #pragma unroll
  for (int j = 0; j < 4; ++j) {
    int col = cb + j * 16;
    float bv = bias[col];
    #pragma unroll
    for (int i = 0; i < 4; ++i) {
      #pragma unroll
      for (int r = 0; r < 4; ++r) {
        size_t idx = (size_t)(rbase + i * 16 + r) * N + col;
        float v = acc[i][j][r] + bv;
        if (FINAL) ofp[idx] = xres[idx] + v;
        else       obf[idx] = f2b(v);
      }
    }
  }
}

// ---------------- banded attention ----------------
// grid (T/64, H, B), 256 threads. Per block: 64 q-rows of one (b,h),
// K/V rows t0-16 .. t0+79 (96 rows), dh=64.
__global__ __launch_bounds__(256) void attn_k(const unsigned short* __restrict__ qkv,
                                              unsigned short* __restrict__ obuf) {
  __shared__ unsigned short Ks[96 * 72];    // K rows, row-major, stride 72 (144B: conflict-optimal)
  __shared__ unsigned short Vt[64 * 128];   // V transposed [d][r-units swizzled]
  __shared__ unsigned short Ps[64 * 104];   // P [t_local][r], padded
  int tid = threadIdx.x;
  int lane = tid & 63, wave = tid >> 6;
  int fr = lane & 15, fq = lane >> 4;
  int t0 = blockIdx.x * 64;
  int hh = blockIdx.y;
  int bb = blockIdx.z;
  size_t rowbase = (size_t)bb * T_;

  // stage K (row-major) and V (transposed, unit-swizzled).
  // c = r*8 + u: 8 consecutive lanes read one contiguous 128B row -> coalesced.
  #pragma unroll
  for (int it = 0; it < 3; ++it) {
    int c = tid + it * 256;       // 0..767
    int r = c >> 3;               // 0..95
    int u = c & 7;
    int d8 = u * 8;
    int tg = t0 - BAND + r;
    us8 kv = {0,0,0,0,0,0,0,0}, vv = {0,0,0,0,0,0,0,0};
    if (tg >= 0 && tg < T_) {
      const unsigned short* p = qkv + (rowbase + tg) * 1536 + hh * 64 + d8;
      kv = *(const us8*)(p + 512);
      vv = *(const us8*)(p + 1024);
    }
    *(us8*)(Ks + r * 72 + d8) = kv;
    int ru = r >> 3, rl = r & 7;
    #pragma unroll
    for (int j = 0; j < 8; ++j)
      Vt[(d8 + j) * 128 + (((ru ^ u) << 3) | rl)] = vv[j];
  }

  // Q fragments straight from global (A-frag: row=fr, k=8*fq)
  bf16x8 qf0, qf1;
  {
    int tq = t0 + wave * 16 + fr;
    const unsigned short* qp = qkv + (rowbase + tq) * 1536 + hh * 64 + fq * 8;
    qf0 = *(const bf16x8*)qp;
    qf1 = *(const bf16x8*)(qp + 32);
  }
  __syncthreads();

  // S = Q K^T  (per wave: 16 rows x 96 cols)
  f32x4 sa[6];
  #pragma unroll
  for (int c = 0; c < 6; ++c) sa[c] = (f32x4){0.f, 0.f, 0.f, 0.f};
  #pragma unroll
  for (int c = 0; c < 6; ++c) {
    bf16x8 k0 = *(const bf16x8*)(Ks + (c * 16 + fr) * 72 + fq * 8);
    bf16x8 k1 = *(const bf16x8*)(Ks + (c * 16 + fr) * 72 + 32 + fq * 8);
    sa[c] = mfma16(qf0, k0, sa[c]);
    sa[c] = mfma16(qf1, k1, sa[c]);
  }

  // banded mask + row softmax (rows live on 16-lane groups)
  float inv[4];
  float pvv[6][4];
  #pragma unroll
  for (int r = 0; r < 4; ++r) {
    int tg = t0 + wave * 16 + fq * 4 + r;
    float m = -1e30f;
    #pragma unroll
    for (int c = 0; c < 6; ++c) {
      int cg = t0 - BAND + c * 16 + fr;
      bool ok = (cg >= tg - BAND) && (cg <= tg + BAND) && (cg >= 0) && (cg < T_);
      float v = ok ? sa[c][r] * 0.125f : -1e30f;
      pvv[c][r] = v;
      m = fmaxf(m, v);
    }
    #pragma unroll
    for (int o = 8; o; o >>= 1) m = fmaxf(m, __shfl_xor(m, o, 64));
    float s = 0.0f;
    #pragma unroll
    for (int c = 0; c < 6; ++c) {
      float e = exp2f((pvv[c][r] - m) * 1.44269504f);
      pvv[c][r] = e;
      s += e;
    }
    #pragma unroll
    for (int o = 8; o; o >>= 1) s += __shfl_xor(s, o, 64);
    inv[r] = 1.0f / s;
  }

  // P -> LDS (bf16) for PV A-frags
  #pragma unroll
  for (int c = 0; c < 6; ++c)
    #pragma unroll
    for (int r = 0; r < 4; ++r)
      Ps[(wave * 16 + fq * 4 + r) * 104 + c * 16 + fr] = f2b(pvv[c][r]);

  __syncthreads();

  // O = P V   (B-frag: lane fr = out col d, k contiguous; Vt unit-swizzled)
  f32x4 oa[4];
  #pragma unroll
  for (int c2 = 0; c2 < 4; ++c2) oa[c2] = (f32x4){0.f, 0.f, 0.f, 0.f};
  #pragma unroll
  for (int kk = 0; kk < 3; ++kk) {
    bf16x8 pa = *(const bf16x8*)(Ps + (wave * 16 + fr) * 104 + kk * 32 + fq * 8);
    #pragma unroll
    for (int c2 = 0; c2 < 4; ++c2) {
      int drow = c2 * 16 + fr;
      int ud = (drow >> 3) & 7;
      bf16x8 vb = *(const bf16x8*)(Vt + drow * 128 + (((kk * 4 + fq) ^ ud) << 3));
      oa[c2] = mfma16(pa, vb, oa[c2]);
    }
  }

  size_t orow = rowbase + t0 + wave * 16 + fq * 4;
  #pragma unroll
  for (int c2 = 0; c2 < 4; ++c2)
    #pragma unroll
    for (int r = 0; r < 4; ++r)
      obuf[(orow + r) * D_ + hh * 64 + c2 * 16 + fr] = f2b(oa[c2][r] * inv[r]);
}

extern "C" void kernel_launch(void* const* d_in, const int* in_sizes, int n_in,
                              void* d_out, int out_size, void* d_ws, size_t ws_size,
                              hipStream_t stream) {
  (void)in_sizes; (void)n_in; (void)out_size; (void)ws_size;
  const float* x     = (const float*)d_in[0];
  const float* ln_g  = (const float*)d_in[1];
  const float* ln_b  = (const float*)d_in[2];
  const float* w_in  = (const float*)d_in[3];
  const float* b_in  = (const float*)d_in[4];
  const float* w_out = (const float*)d_in[5];
  const float* b_out = (const float*)d_in[6];
  float* out = (float*)d_out;

  char* ws = (char*)d_ws;
  unsigned short* hb    = (unsigned short*)(ws);              // 8192*512   bf16  (8 MB)
  unsigned short* winb  = (unsigned short*)(ws + 8388608);    // 1536*512   bf16
  unsigned short* woutb = (unsigned short*)(ws + 9961472);    // 512*512    bf16
  unsigned short* qkvb  = (unsigned short*)(ws + 10485760);   // 8192*1536  bf16  (24 MB)
  unsigned short* obf   = (unsigned short*)(ws + 35651584);   // 8192*512   bf16  (8 MB)

  prep_k<<<3072, 256, 0, stream>>>(x, ln_g, ln_b, w_in, w_out, hb, winb, woutb);
  gemm_bt<false><<<dim3(64, 12), 256, 0, stream>>>(hb, winb, b_in, nullptr, qkvb, nullptr, 1536, 512);
  attn_k<<<dim3(64, 8, 2), 256, 0, stream>>>(qkvb, obf);
  gemm_bt<true><<<dim3(64, 4), 256, 0, stream>>>(obf, woutb, b_out, x, nullptr, out, 512, 512);
}

// Round 3
// 61.931 us; speedup vs baseline: 1.2754x; 1.0725x over previous
//
#include <hip/hip_runtime.h>
#include <hip/hip_bf16.h>

#define T_ 4096
#define D_ 512
#define H_ 8
#define BAND 16
#define G1_K 512
#define G1_NT 8   // K / 64

typedef float f32x4 __attribute__((ext_vector_type(4)));
typedef __bf16 bf16x8 __attribute__((ext_vector_type(8)));
typedef unsigned short us8 __attribute__((ext_vector_type(8)));
typedef unsigned short us4 __attribute__((ext_vector_type(4)));

__device__ __forceinline__ unsigned short f2b(float f) {
  union { float f; unsigned u; } v; v.f = f;
  unsigned r = v.u + 0x7fffu + ((v.u >> 16) & 1u);
  return (unsigned short)(r >> 16);
}

__device__ __forceinline__ f32x4 mfma16(bf16x8 a, bf16x8 b, f32x4 c) {
  return __builtin_amdgcn_mfma_f32_16x16x32_bf16(a, b, c, 0, 0, 0);
}

#define GLD16(gp, lp) __builtin_amdgcn_global_load_lds( \
    (const __attribute__((address_space(1))) void*)(gp), \
    (__attribute__((address_space(3))) void*)(lp), 16, 0, 0)

// ---------------- fused: weight fp32->bf16 cvt + LayerNorm ----------------
__global__ __launch_bounds__(256) void prep_k(const float* __restrict__ x,
                                              const float* __restrict__ g,
                                              const float* __restrict__ bt,
                                              const float* __restrict__ win,
                                              const float* __restrict__ wout,
                                              unsigned short* __restrict__ h,
                                              unsigned short* __restrict__ winb,
                                              unsigned short* __restrict__ woutb) {
  int bx = blockIdx.x;
  if (bx >= 2048) {
    int i = (bx - 2048) * 256 + threadIdx.x;
    const int n1 = 3 * D_ * D_ / 4;
    if (i < n1) {
      float4 v = ((const float4*)win)[i];
      us4 o; o.x = f2b(v.x); o.y = f2b(v.y); o.z = f2b(v.z); o.w = f2b(v.w);
      ((us4*)winb)[i] = o;
    } else {
      int j = i - n1;
      float4 v = ((const float4*)wout)[j];
      us4 o; o.x = f2b(v.x); o.y = f2b(v.y); o.z = f2b(v.z); o.w = f2b(v.w);
      ((us4*)woutb)[j] = o;
    }
    return;
  }
  int wave = threadIdx.x >> 6, lane = threadIdx.x & 63;
  size_t row = (size_t)bx * 4 + wave;
  const float4* xr = (const float4*)(x + row * D_);
  float4 a = xr[lane * 2], b = xr[lane * 2 + 1];
  float s = a.x + a.y + a.z + a.w + b.x + b.y + b.z + b.w;
  #pragma unroll
  for (int o = 32; o; o >>= 1) s += __shfl_xor(s, o, 64);
  float mu = s * (1.0f / D_);
  float d0 = a.x - mu, d1 = a.y - mu, d2 = a.z - mu, d3 = a.w - mu;
  float d4 = b.x - mu, d5 = b.y - mu, d6 = b.z - mu, d7 = b.w - mu;
  float q = d0*d0 + d1*d1 + d2*d2 + d3*d3 + d4*d4 + d5*d5 + d6*d6 + d7*d7;
  #pragma unroll
  for (int o = 32; o; o >>= 1) q += __shfl_xor(q, o, 64);
  float rstd = rsqrtf(q * (1.0f / D_) + 1e-5f);
  const float4* gr = (const float4*)g;
  const float4* br = (const float4*)bt;
  float4 g0 = gr[lane * 2], g1 = gr[lane * 2 + 1];
  float4 b0 = br[lane * 2], b1 = br[lane * 2 + 1];
  us8 o8;
  o8[0] = f2b(d0 * rstd * g0.x + b0.x);
  o8[1] = f2b(d1 * rstd * g0.y + b0.y);
  o8[2] = f2b(d2 * rstd * g0.z + b0.z);
  o8[3] = f2b(d3 * rstd * g0.w + b0.w);
  o8[4] = f2b(d4 * rstd * g1.x + b1.x);
  o8[5] = f2b(d5 * rstd * g1.y + b1.y);
  o8[6] = f2b(d6 * rstd * g1.z + b1.z);
  o8[7] = f2b(d7 * rstd * g1.w + b1.w);
  *((us8*)(h + row * D_) + lane) = o8;
}

// ============ GEMM1: 8-phase 256x256 BK=64, 8 waves, qkv = h @ w_in^T + b ============
// LDS (dyn 128KB), elem offsets: slot*32768 + op*16384 (op: A=0,B=1) + half*8192
//                               + row_local*64 + unit*8 ; staged unit u holds
//                               global k-unit (u ^ (row_local&7)).
#define OPA 0
#define OPB 1

__device__ __forceinline__ void stg(const unsigned short* __restrict__ gb,
                                    unsigned short* lds, int slot, int op, int h, int tt,
                                    int rl0, int u0, int su) {
  #pragma unroll
  for (int j = 0; j < 2; ++j) {
    const unsigned short* g = gb + (size_t)(h * 128 + rl0 + 64 * j) * G1_K + tt * 64 + su;
    unsigned short* lp = lds + slot * 32768 + op * 16384 + h * 8192 + (rl0 + 64 * j) * 64 + u0 * 8;
    GLD16(g, lp);
  }
}

#define VMC4 asm volatile("s_waitcnt vmcnt(4)" ::: "memory")
#define VMC0 asm volatile("s_waitcnt vmcnt(0)" ::: "memory")

// one phase: read frags for m-pair (2*PH,2*PH+1) [+ B-frags if PH==0], issue stage,
// bar, lgkm0, 16 MFMA, optional vmcnt, bar.
#define PHASE(SLOT, PH, STAGE_STMT, WAIT_STMT) do {                                        \
    if ((PH) == 0) {                                                                       \
      _Pragma("unroll") for (int nf = 0; nf < 4; ++nf) {                                   \
        breg[nf][0] = *(const bf16x8*)(lds + (SLOT)*32768 + boff + nf*1024 + swz0);        \
        breg[nf][1] = *(const bf16x8*)(lds + (SLOT)*32768 + boff + nf*1024 + swz1);        \
      }                                                                                    \
    }                                                                                      \
    bf16x8 a0k0 = *(const bf16x8*)(lds + (SLOT)*32768 + aoff + (2*(PH))*1024 + swz0);      \
    bf16x8 a0k1 = *(const bf16x8*)(lds + (SLOT)*32768 + aoff + (2*(PH))*1024 + swz1);      \
    bf16x8 a1k0 = *(const bf16x8*)(lds + (SLOT)*32768 + aoff + (2*(PH)+1)*1024 + swz0);    \
    bf16x8 a1k1 = *(const bf16x8*)(lds + (SLOT)*32768 + aoff + (2*(PH)+1)*1024 + swz1);    \
    STAGE_STMT;                                                                            \
    __builtin_amdgcn_s_barrier();                                                          \
    asm volatile("s_waitcnt lgkmcnt(0)" ::: "memory");                                     \
    __builtin_amdgcn_sched_barrier(0);                                                     \
    __builtin_amdgcn_s_setprio(1);                                                         \
    _Pragma("unroll") for (int nf = 0; nf < 4; ++nf) {                                     \
      acc[2*(PH)][nf]   = mfma16(a0k0, breg[nf][0], acc[2*(PH)][nf]);                      \
      acc[2*(PH)][nf]   = mfma16(a0k1, breg[nf][1], acc[2*(PH)][nf]);                      \
      acc[2*(PH)+1][nf] = mfma16(a1k0, breg[nf][0], acc[2*(PH)+1][nf]);                    \
      acc[2*(PH)+1][nf] = mfma16(a1k1, breg[nf][1], acc[2*(PH)+1][nf]);                    \
    }                                                                                      \
    __builtin_amdgcn_s_setprio(0);                                                         \
    __builtin_amdgcn_sched_barrier(0);                                                     \
    WAIT_STMT;                                                                             \
    __builtin_amdgcn_s_barrier();                                                          \
  } while (0)

__global__ __launch_bounds__(512, 2) void gemm_qkv8(const unsigned short* __restrict__ A,
                                                    const unsigned short* __restrict__ Bw,
                                                    const float* __restrict__ bias,
                                                    unsigned short* __restrict__ C) {
  extern __shared__ char smem[];
  unsigned short* lds = (unsigned short*)smem;
  int tid = threadIdx.x;
  int lane = tid & 63, wave = tid >> 6;
  int wm = wave >> 2, wn = wave & 3;
  int fr = lane & 15, fq = lane >> 4;
  // bijective XCD swizzle: 192 blocks = 8 xcd * 24
  int d = blockIdx.x;
  int l = (d & 7) * 24 + (d >> 3);
  int bm = l / 6, bn = l % 6;

  const unsigned short* Ag = A + (size_t)bm * 256 * G1_K;
  const unsigned short* Bg = Bw + (size_t)bn * 256 * G1_K;

  int rl0 = tid >> 3, u0 = tid & 7;
  int su = (u0 ^ (rl0 & 7)) * 8;

  int aoff = wm * 8192 + fr * 64;                                   // op A, half wm
  int boff = 16384 + (wn >> 1) * 8192 + ((wn & 1) * 64 + fr) * 64;  // op B
  int swz0 = (fq ^ (fr & 7)) * 8;
  int swz1 = ((4 + fq) ^ (fr & 7)) * 8;

  f32x4 acc[8][4] = {};
  bf16x8 breg[4][2];

  // prologue: t0 all 4 halves, then t1.B halves
  stg(Bg, lds, 0, OPB, 0, 0, rl0, u0, su);
  stg(Bg, lds, 0, OPB, 1, 0, rl0, u0, su);
  stg(Ag, lds, 0, OPA, 0, 0, rl0, u0, su);
  stg(Ag, lds, 0, OPA, 1, 0, rl0, u0, su);
  stg(Bg, lds, 1, OPB, 0, 1, rl0, u0, su);
  stg(Bg, lds, 1, OPB, 1, 1, rl0, u0, su);
  VMC4;                       // t0's 8 loads landed (t1.B may fly)
  __builtin_amdgcn_s_barrier();

  #pragma unroll 1
  for (int i = 0; i < 3; ++i) {
    int t = 2 * i;
    PHASE(0, 0, stg(Ag, lds, 1, OPA, 0, t + 1, rl0, u0, su), (void)0);
    PHASE(0, 1, stg(Ag, lds, 1, OPA, 1, t + 1, rl0, u0, su), (void)0);
    PHASE(0, 2, stg(Bg, lds, 0, OPB, 0, t + 2, rl0, u0, su), (void)0);
    PHASE(0, 3, stg(Bg, lds, 0, OPB, 1, t + 2, rl0, u0, su), VMC4);
    PHASE(1, 0, stg(Ag, lds, 0, OPA, 0, t + 2, rl0, u0, su), (void)0);
    PHASE(1, 1, stg(Ag, lds, 0, OPA, 1, t + 2, rl0, u0, su), (void)0);
    PHASE(1, 2, stg(Bg, lds, 1, OPB, 0, t + 3, rl0, u0, su), (void)0);
    PHASE(1, 3, stg(Bg, lds, 1, OPB, 1, t + 3, rl0, u0, su), VMC4);
  }
  // tail: tiles 6,7
  PHASE(0, 0, stg(Ag, lds, 1, OPA, 0, 7, rl0, u0, su), (void)0);
  PHASE(0, 1, stg(Ag, lds, 1, OPA, 1, 7, rl0, u0, su), (void)0);
  PHASE(0, 2, (void)0, (void)0);
  PHASE(0, 3, (void)0, VMC0);
  PHASE(1, 0, (void)0, (void)0);
  PHASE(1, 1, (void)0, (void)0);
  PHASE(1, 2, (void)0, (void)0);
  PHASE(1, 3, (void)0, (void)0);

  // epilogue
  int rbase = bm * 256 + wm * 128 + fq * 4;
  int cbase = bn * 256 + wn * 64 + fr;
  float bv[4];
  #pragma unroll
  for (int nf = 0; nf < 4; ++nf) bv[nf] = bias[cbase + nf * 16];
  #pragma unroll
  for (int mf = 0; mf < 8; ++mf)
    #pragma unroll
    for (int nf = 0; nf < 4; ++nf)
      #pragma unroll
      for (int r = 0; r < 4; ++r)
        C[(size_t)(rbase + mf * 16 + r) * 1536 + cbase + nf * 16] = f2b(acc[mf][nf][r] + bv[nf]);
}

// ---------------- GEMM2 (128x128, m97 structure) C = A @ Bw^T + bias, +residual ----------------
__global__ __launch_bounds__(256) void gemm_bt2(const unsigned short* __restrict__ A,
                                                const unsigned short* __restrict__ Bw,
                                                const float* __restrict__ bias,
                                                const float* __restrict__ xres,
                                                float* __restrict__ ofp,
                                                int N, int K) {
  __shared__ unsigned short As[128 * 64];
  __shared__ unsigned short Bs[128 * 64];
  int tid = threadIdx.x;
  int lane = tid & 63;
  int wave = tid >> 6;
  int wm = wave >> 1, wn = wave & 1;
  int fr = lane & 15, fq = lane >> 4;
  // bijective XCD swizzle (grid 256 = 8*32), bn-count = N/128
  int dd = blockIdx.x;
  int nbn = N >> 7;
  int l = (dd & 7) * (gridDim.x >> 3) + (dd >> 3);
  int bm = l / nbn, bn = l % nbn;

  const unsigned short* Ap[4];
  const unsigned short* Bp[4];
  int loff[4];
  #pragma unroll
  for (int g = 0; g < 4; ++g) {
    int s = g * 256 + tid;
    int row = s >> 3, u = s & 7;
    int uu = u ^ (row & 7);
    Ap[g] = A + (size_t)(bm * 128 + row) * K + uu * 8;
    Bp[g] = Bw + (size_t)(bn * 128 + row) * K + uu * 8;
    loff[g] = s * 16;
  }

  f32x4 acc[4][4] = {};

  int nk = K >> 6;
  for (int kt = 0; kt < nk; ++kt) {
    int ko = kt * 64;
    #pragma unroll
    for (int g = 0; g < 4; ++g) GLD16(Ap[g] + ko, (char*)As + loff[g]);
    #pragma unroll
    for (int g = 0; g < 4; ++g) GLD16(Bp[g] + ko, (char*)Bs + loff[g]);
    __syncthreads();
    #pragma unroll
    for (int kk = 0; kk < 2; ++kk) {
      bf16x8 af[4], bfr[4];
      #pragma unroll
      for (int i = 0; i < 4; ++i) {
        int row = wm * 64 + i * 16 + fr;
        af[i] = *(const bf16x8*)(As + row * 64 + (((kk * 4 + fq) ^ (fr & 7)) << 3));
      }
      #pragma unroll
      for (int j = 0; j < 4; ++j) {
        int row = wn * 64 + j * 16 + fr;
        bfr[j] = *(const bf16x8*)(Bs + row * 64 + (((kk * 4 + fq) ^ (fr & 7)) << 3));
      }
      #pragma unroll
      for (int i = 0; i < 4; ++i)
        #pragma unroll
        for (int j = 0; j < 4; ++j)
          acc[i][j] = mfma16(af[i], bfr[j], acc[i][j]);
    }
    __syncthreads();
  }

  int rbase = bm * 128 + wm * 64 + fq * 4;
  int cb = bn * 128 + wn * 64 + fr;
  #pragma unroll
  for (int j = 0; j < 4; ++j) {
    int col = cb + j * 16;
    float bvv = bias[col];
    #pragma unroll
    for (int i = 0; i < 4; ++i) {
      #pragma unroll
      for (int r = 0; r < 4; ++r) {
        size_t idx = (size_t)(rbase + i * 16 + r) * N + col;
        ofp[idx] = xres[idx] + acc[i][j][r] + bvv;
      }
    }
  }
}

// ---------------- banded attention ----------------
__global__ __launch_bounds__(256) void attn_k(const unsigned short* __restrict__ qkv,
                                              unsigned short* __restrict__ obuf) {
  __shared__ unsigned short Ks[96 * 72];
  __shared__ unsigned short Vt[64 * 128];
  __shared__ unsigned short Ps[64 * 104];
  int tid = threadIdx.x;
  int lane = tid & 63, wave = tid >> 6;
  int fr = lane & 15, fq = lane >> 4;
  int t0 = blockIdx.x * 64;
  int hh = blockIdx.y;
  int bb = blockIdx.z;
  size_t rowbase = (size_t)bb * T_;

  #pragma unroll
  for (int it = 0; it < 3; ++it) {
    int c = tid + it * 256;
    int r = c >> 3;
    int u = c & 7;
    int d8 = u * 8;
    int tg = t0 - BAND + r;
    us8 kv = {0,0,0,0,0,0,0,0}, vv = {0,0,0,0,0,0,0,0};
    if (tg >= 0 && tg < T_) {
      const unsigned short* p = qkv + (rowbase + tg) * 1536 + hh * 64 + d8;
      kv = *(const us8*)(p + 512);
      vv = *(const us8*)(p + 1024);
    }
    *(us8*)(Ks + r * 72 + d8) = kv;
    int ru = r >> 3, rl = r & 7;
    #pragma unroll
    for (int j = 0; j < 8; ++j)
      Vt[(d8 + j) * 128 + (((ru ^ u) << 3) | rl)] = vv[j];
  }

  bf16x8 qf0, qf1;
  {
    int tq = t0 + wave * 16 + fr;
    const unsigned short* qp = qkv + (rowbase + tq) * 1536 + hh * 64 + fq * 8;
    qf0 = *(const bf16x8*)qp;
    qf1 = *(const bf16x8*)(qp + 32);
  }
  __syncthreads();

  f32x4 sa[6];
  #pragma unroll
  for (int c = 0; c < 6; ++c) sa[c] = (f32x4){0.f, 0.f, 0.f, 0.f};
  #pragma unroll
  for (int c = 0; c < 6; ++c) {
    bf16x8 k0 = *(const bf16x8*)(Ks + (c * 16 + fr) * 72 + fq * 8);
    bf16x8 k1 = *(const bf16x8*)(Ks + (c * 16 + fr) * 72 + 32 + fq * 8);
    sa[c] = mfma16(qf0, k0, sa[c]);
    sa[c] = mfma16(qf1, k1, sa[c]);
  }

  float inv[4];
  float pvv[6][4];
  #pragma unroll
  for (int r = 0; r < 4; ++r) {
    int tg = t0 + wave * 16 + fq * 4 + r;
    float m = -1e30f;
    #pragma unroll
    for (int c = 0; c < 6; ++c) {
      int cg = t0 - BAND + c * 16 + fr;
      bool ok = (cg >= tg - BAND) && (cg <= tg + BAND) && (cg >= 0) && (cg < T_);
      float v = ok ? sa[c][r] * 0.125f : -1e30f;
      pvv[c][r] = v;
      m = fmaxf(m, v);
    }
    #pragma unroll
    for (int o = 8; o; o >>= 1) m = fmaxf(m, __shfl_xor(m, o, 64));
    float s = 0.0f;
    #pragma unroll
    for (int c = 0; c < 6; ++c) {
      float e = exp2f((pvv[c][r] - m) * 1.44269504f);
      pvv[c][r] = e;
      s += e;
    }
    #pragma unroll
    for (int o = 8; o; o >>= 1) s += __shfl_xor(s, o, 64);
    inv[r] = 1.0f / s;
  }

  #pragma unroll
  for (int c = 0; c < 6; ++c)
    #pragma unroll
    for (int r = 0; r < 4; ++r)
      Ps[(wave * 16 + fq * 4 + r) * 104 + c * 16 + fr] = f2b(pvv[c][r]);

  __syncthreads();

  f32x4 oa[4];
  #pragma unroll
  for (int c2 = 0; c2 < 4; ++c2) oa[c2] = (f32x4){0.f, 0.f, 0.f, 0.f};
  #pragma unroll
  for (int kk = 0; kk < 3; ++kk) {
    bf16x8 pa = *(const bf16x8*)(Ps + (wave * 16 + fr) * 104 + kk * 32 + fq * 8);
    #pragma unroll
    for (int c2 = 0; c2 < 4; ++c2) {
      int drow = c2 * 16 + fr;
      int ud = (drow >> 3) & 7;
      bf16x8 vb = *(const bf16x8*)(Vt + drow * 128 + (((kk * 4 + fq) ^ ud) << 3));
      oa[c2] = mfma16(pa, vb, oa[c2]);
    }
  }

  size_t orow = rowbase + t0 + wave * 16 + fq * 4;
  #pragma unroll
  for (int c2 = 0; c2 < 4; ++c2)
    #pragma unroll
    for (int r = 0; r < 4; ++r)
      obuf[(orow + r) * D_ + hh * 64 + c2 * 16 + fr] = f2b(oa[c2][r] * inv[r]);
}

extern "C" void kernel_launch(void* const* d_in, const int* in_sizes, int n_in,
                              void* d_out, int out_size, void* d_ws, size_t ws_size,
                              hipStream_t stream) {
  (void)in_sizes; (void)n_in; (void)out_size; (void)ws_size;
  const float* x     = (const float*)d_in[0];
  const float* ln_g  = (const float*)d_in[1];
  const float* ln_b  = (const float*)d_in[2];
  const float* w_in  = (const float*)d_in[3];
  const float* b_in  = (const float*)d_in[4];
  const float* w_out = (const float*)d_in[5];
  const float* b_out = (const float*)d_in[6];
  float* out = (float*)d_out;

  char* ws = (char*)d_ws;
  unsigned short* hb    = (unsigned short*)(ws);              // 8192*512   bf16
  unsigned short* winb  = (unsigned short*)(ws + 8388608);    // 1536*512   bf16
  unsigned short* woutb = (unsigned short*)(ws + 9961472);    // 512*512    bf16
  unsigned short* qkvb  = (unsigned short*)(ws + 10485760);   // 8192*1536  bf16
  unsigned short* obf   = (unsigned short*)(ws + 35651584);   // 8192*512   bf16

  (void)hipFuncSetAttribute((const void*)gemm_qkv8,
                            hipFuncAttributeMaxDynamicSharedMemorySize, 131072);

  prep_k<<<3072, 256, 0, stream>>>(x, ln_g, ln_b, w_in, w_out, hb, winb, woutb);
  gemm_qkv8<<<192, 512, 131072, stream>>>(hb, winb, b_in, qkvb);
  attn_k<<<dim3(64, 8, 2), 256, 0, stream>>>(qkvb, obf);
  gemm_bt2<<<256, 256, 0, stream>>>(obf, woutb, b_out, x, out, 512, 512);
}

// Round 4
// 61.772 us; speedup vs baseline: 1.2787x; 1.0026x over previous
//
#include <hip/hip_runtime.h>
#include <hip/hip_bf16.h>

#define T_ 4096
#define D_ 512
#define H_ 8
#define BAND 16
#define G1_K 512

typedef float f32x4 __attribute__((ext_vector_type(4)));
typedef __bf16 bf16x8 __attribute__((ext_vector_type(8)));
typedef unsigned short us8 __attribute__((ext_vector_type(8)));
typedef unsigned short us4 __attribute__((ext_vector_type(4)));

__device__ __forceinline__ unsigned short f2b(float f) {
  union { float f; unsigned u; } v; v.f = f;
  unsigned r = v.u + 0x7fffu + ((v.u >> 16) & 1u);
  return (unsigned short)(r >> 16);
}

__device__ __forceinline__ f32x4 mfma16(bf16x8 a, bf16x8 b, f32x4 c) {
  return __builtin_amdgcn_mfma_f32_16x16x32_bf16(a, b, c, 0, 0, 0);
}

#define GLD16(gp, lp) __builtin_amdgcn_global_load_lds( \
    (const __attribute__((address_space(1))) void*)(gp), \
    (__attribute__((address_space(3))) void*)(lp), 16, 0, 0)

// ---------------- fused: weight fp32->bf16 cvt + LayerNorm ----------------
__global__ __launch_bounds__(256) void prep_k(const float* __restrict__ x,
                                              const float* __restrict__ g,
                                              const float* __restrict__ bt,
                                              const float* __restrict__ win,
                                              const float* __restrict__ wout,
                                              unsigned short* __restrict__ h,
                                              unsigned short* __restrict__ winb,
                                              unsigned short* __restrict__ woutb) {
  int bx = blockIdx.x;
  if (bx >= 2048) {
    int i = (bx - 2048) * 256 + threadIdx.x;
    const int n1 = 3 * D_ * D_ / 4;
    if (i < n1) {
      float4 v = ((const float4*)win)[i];
      us4 o; o.x = f2b(v.x); o.y = f2b(v.y); o.z = f2b(v.z); o.w = f2b(v.w);
      ((us4*)winb)[i] = o;
    } else {
      int j = i - n1;
      float4 v = ((const float4*)wout)[j];
      us4 o; o.x = f2b(v.x); o.y = f2b(v.y); o.z = f2b(v.z); o.w = f2b(v.w);
      ((us4*)woutb)[j] = o;
    }
    return;
  }
  int wave = threadIdx.x >> 6, lane = threadIdx.x & 63;
  size_t row = (size_t)bx * 4 + wave;
  const float4* xr = (const float4*)(x + row * D_);
  float4 a = xr[lane * 2], b = xr[lane * 2 + 1];
  float s = a.x + a.y + a.z + a.w + b.x + b.y + b.z + b.w;
  #pragma unroll
  for (int o = 32; o; o >>= 1) s += __shfl_xor(s, o, 64);
  float mu = s * (1.0f / D_);
  float d0 = a.x - mu, d1 = a.y - mu, d2 = a.z - mu, d3 = a.w - mu;
  float d4 = b.x - mu, d5 = b.y - mu, d6 = b.z - mu, d7 = b.w - mu;
  float q = d0*d0 + d1*d1 + d2*d2 + d3*d3 + d4*d4 + d5*d5 + d6*d6 + d7*d7;
  #pragma unroll
  for (int o = 32; o; o >>= 1) q += __shfl_xor(q, o, 64);
  float rstd = rsqrtf(q * (1.0f / D_) + 1e-5f);
  const float4* gr = (const float4*)g;
  const float4* br = (const float4*)bt;
  float4 g0 = gr[lane * 2], g1 = gr[lane * 2 + 1];
  float4 b0 = br[lane * 2], b1 = br[lane * 2 + 1];
  us8 o8;
  o8[0] = f2b(d0 * rstd * g0.x + b0.x);
  o8[1] = f2b(d1 * rstd * g0.y + b0.y);
  o8[2] = f2b(d2 * rstd * g0.z + b0.z);
  o8[3] = f2b(d3 * rstd * g0.w + b0.w);
  o8[4] = f2b(d4 * rstd * g1.x + b1.x);
  o8[5] = f2b(d5 * rstd * g1.y + b1.y);
  o8[6] = f2b(d6 * rstd * g1.z + b1.z);
  o8[7] = f2b(d7 * rstd * g1.w + b1.w);
  *((us8*)(h + row * D_) + lane) = o8;
}

// ============ GEMM1: 8-phase 256x256 BK=64, 8 waves, qkv = h @ w_in^T + b ============
#define OPA 0
#define OPB 1

__device__ __forceinline__ void stg(const unsigned short* __restrict__ gb,
                                    unsigned short* lds, int slot, int op, int h, int tt,
                                    int rl0, int u0, int su) {
  #pragma unroll
  for (int j = 0; j < 2; ++j) {
    const unsigned short* g = gb + (size_t)(h * 128 + rl0 + 64 * j) * G1_K + tt * 64 + su;
    unsigned short* lp = lds + slot * 32768 + op * 16384 + h * 8192 + (rl0 + 64 * j) * 64 + u0 * 8;
    GLD16(g, lp);
  }
}

#define VMC4 asm volatile("s_waitcnt vmcnt(4)" ::: "memory")
#define VMC0 asm volatile("s_waitcnt vmcnt(0)" ::: "memory")

#define PHASE(SLOT, PH, STAGE_STMT, WAIT_STMT) do {                                        \
    if ((PH) == 0) {                                                                       \
      _Pragma("unroll") for (int nf = 0; nf < 4; ++nf) {                                   \
        breg[nf][0] = *(const bf16x8*)(lds + (SLOT)*32768 + boff + nf*1024 + swz0);        \
        breg[nf][1] = *(const bf16x8*)(lds + (SLOT)*32768 + boff + nf*1024 + swz1);        \
      }                                                                                    \
    }                                                                                      \
    bf16x8 a0k0 = *(const bf16x8*)(lds + (SLOT)*32768 + aoff + (2*(PH))*1024 + swz0);      \
    bf16x8 a0k1 = *(const bf16x8*)(lds + (SLOT)*32768 + aoff + (2*(PH))*1024 + swz1);      \
    bf16x8 a1k0 = *(const bf16x8*)(lds + (SLOT)*32768 + aoff + (2*(PH)+1)*1024 + swz0);    \
    bf16x8 a1k1 = *(const bf16x8*)(lds + (SLOT)*32768 + aoff + (2*(PH)+1)*1024 + swz1);    \
    STAGE_STMT;                                                                            \
    __builtin_amdgcn_s_barrier();                                                          \
    asm volatile("s_waitcnt lgkmcnt(0)" ::: "memory");                                     \
    __builtin_amdgcn_sched_barrier(0);                                                     \
    __builtin_amdgcn_s_setprio(1);                                                         \
    _Pragma("unroll") for (int nf = 0; nf < 4; ++nf) {                                     \
      acc[2*(PH)][nf]   = mfma16(a0k0, breg[nf][0], acc[2*(PH)][nf]);                      \
      acc[2*(PH)][nf]   = mfma16(a0k1, breg[nf][1], acc[2*(PH)][nf]);                      \
      acc[2*(PH)+1][nf] = mfma16(a1k0, breg[nf][0], acc[2*(PH)+1][nf]);                    \
      acc[2*(PH)+1][nf] = mfma16(a1k1, breg[nf][1], acc[2*(PH)+1][nf]);                    \
    }                                                                                      \
    __builtin_amdgcn_s_setprio(0);                                                         \
    __builtin_amdgcn_sched_barrier(0);                                                     \
    WAIT_STMT;                                                                             \
    __builtin_amdgcn_s_barrier();                                                          \
  } while (0)

__global__ __launch_bounds__(512, 2) void gemm_qkv8(const unsigned short* __restrict__ A,
                                                    const unsigned short* __restrict__ Bw,
                                                    const float* __restrict__ bias,
                                                    unsigned short* __restrict__ C) {
  extern __shared__ char smem[];
  unsigned short* lds = (unsigned short*)smem;
  int tid = threadIdx.x;
  int lane = tid & 63, wave = tid >> 6;
  int wm = wave >> 2, wn = wave & 3;
  int fr = lane & 15, fq = lane >> 4;
  int d = blockIdx.x;
  int l = (d & 7) * 24 + (d >> 3);
  int bm = l / 6, bn = l % 6;

  const unsigned short* Ag = A + (size_t)bm * 256 * G1_K;
  const unsigned short* Bg = Bw + (size_t)bn * 256 * G1_K;

  int rl0 = tid >> 3, u0 = tid & 7;
  int su = (u0 ^ (rl0 & 7)) * 8;

  int aoff = wm * 8192 + fr * 64;
  int boff = 16384 + (wn >> 1) * 8192 + ((wn & 1) * 64 + fr) * 64;
  int swz0 = (fq ^ (fr & 7)) * 8;
  int swz1 = ((4 + fq) ^ (fr & 7)) * 8;

  f32x4 acc[8][4] = {};
  bf16x8 breg[4][2];

  stg(Bg, lds, 0, OPB, 0, 0, rl0, u0, su);
  stg(Bg, lds, 0, OPB, 1, 0, rl0, u0, su);
  stg(Ag, lds, 0, OPA, 0, 0, rl0, u0, su);
  stg(Ag, lds, 0, OPA, 1, 0, rl0, u0, su);
  stg(Bg, lds, 1, OPB, 0, 1, rl0, u0, su);
  stg(Bg, lds, 1, OPB, 1, 1, rl0, u0, su);
  VMC4;
  __builtin_amdgcn_s_barrier();

  #pragma unroll 1
  for (int i = 0; i < 3; ++i) {
    int t = 2 * i;
    PHASE(0, 0, stg(Ag, lds, 1, OPA, 0, t + 1, rl0, u0, su), (void)0);
    PHASE(0, 1, stg(Ag, lds, 1, OPA, 1, t + 1, rl0, u0, su), (void)0);
    PHASE(0, 2, stg(Bg, lds, 0, OPB, 0, t + 2, rl0, u0, su), (void)0);
    PHASE(0, 3, stg(Bg, lds, 0, OPB, 1, t + 2, rl0, u0, su), VMC4);
    PHASE(1, 0, stg(Ag, lds, 0, OPA, 0, t + 2, rl0, u0, su), (void)0);
    PHASE(1, 1, stg(Ag, lds, 0, OPA, 1, t + 2, rl0, u0, su), (void)0);
    PHASE(1, 2, stg(Bg, lds, 1, OPB, 0, t + 3, rl0, u0, su), (void)0);
    PHASE(1, 3, stg(Bg, lds, 1, OPB, 1, t + 3, rl0, u0, su), VMC4);
  }
  PHASE(0, 0, stg(Ag, lds, 1, OPA, 0, 7, rl0, u0, su), (void)0);
  PHASE(0, 1, stg(Ag, lds, 1, OPA, 1, 7, rl0, u0, su), (void)0);
  PHASE(0, 2, (void)0, (void)0);
  PHASE(0, 3, (void)0, VMC0);
  PHASE(1, 0, (void)0, (void)0);
  PHASE(1, 1, (void)0, (void)0);
  PHASE(1, 2, (void)0, (void)0);
  PHASE(1, 3, (void)0, (void)0);

  int rbase = bm * 256 + wm * 128 + fq * 4;
  int cbase = bn * 256 + wn * 64 + fr;
  float bv[4];
  #pragma unroll
  for (int nf = 0; nf < 4; ++nf) bv[nf] = bias[cbase + nf * 16];
  #pragma unroll
  for (int mf = 0; mf < 8; ++mf)
    #pragma unroll
    for (int nf = 0; nf < 4; ++nf)
      #pragma unroll
      for (int r = 0; r < 4; ++r)
        C[(size_t)(rbase + mf * 16 + r) * 1536 + cbase + nf * 16] = f2b(acc[mf][nf][r] + bv[nf]);
}

// ============ fused banded attention + out-proj + bias + residual ============
// grid: 256 blocks (B*T/32), 512 threads (8 waves).
// Per block: 32 q-rows (global r0g..r0g+31), K/V window t0-16..t0+47 (64 rows).
// LDS elems: head slot s in 0..3: Ks at s*8192 (64x64, unit^=(r&7)),
//            Vt at s*8192+4096 (64 d-rows x 64, unit^=(d>>3)... see staging);
// P at 32768 + wave*1152 (16 rows x stride 72);
// O at 41984 (32 rows x 512, unit^=(q&7)). Total 58368 elems = 116736 B.
__global__ __launch_bounds__(512, 2) void attn_out_k(const unsigned short* __restrict__ qkv,
                                                     const unsigned short* __restrict__ woutb,
                                                     const float* __restrict__ bout,
                                                     const float* __restrict__ x,
                                                     float* __restrict__ out) {
  extern __shared__ char smem2[];
  unsigned short* lds = (unsigned short*)smem2;
  int tid = threadIdx.x;
  int lane = tid & 63, wave = tid >> 6;
  int fr = lane & 15, fq = lane >> 4;
  int r0g = blockIdx.x * 32;
  int bb = r0g >> 12;
  int t0 = r0g & (T_ - 1);
  size_t rowbase = (size_t)bb * T_;

  unsigned short* Ob = lds + 41984;

  #pragma unroll 1
  for (int rd = 0; rd < 2; ++rd) {
    // ---- stage K/V for heads 4rd..4rd+3 (zero-filled boundaries) ----
    #pragma unroll
    for (int i = 0; i < 8; ++i) {
      int idx = i * 512 + tid;        // 0..4095
      int s   = idx >> 10;            // head slot
      int rem = idx & 1023;
      int ten = rem >> 9;             // 0=K 1=V
      int c   = rem & 511;
      int r   = c >> 3, u = c & 7;
      int hh  = 4 * rd + s;
      int tg  = t0 - BAND + r;
      us8 v8 = {0, 0, 0, 0, 0, 0, 0, 0};
      if (tg >= 0 && tg < T_)
        v8 = *(const us8*)(qkv + (rowbase + tg) * 1536 + (ten ? 1024 : 512) + hh * 64 + u * 8);
      if (ten == 0) {
        *(us8*)(lds + s * 8192 + r * 64 + ((u ^ (r & 7)) << 3)) = v8;
      } else {
        int base = s * 8192 + 4096;
        #pragma unroll
        for (int j = 0; j < 8; ++j)
          lds[base + (u * 8 + j) * 64 + (((r >> 3) ^ u) << 3) + (r & 7)] = v8[j];
      }
    }
    __syncthreads();

    // ---- per-wave unit: head s = wave>>1, q-group qg = wave&1 ----
    {
      int s  = wave >> 1;
      int hh = 4 * rd + s;
      int qg = wave & 1;
      int q  = t0 + qg * 16 + fr;     // this lane's query row (as B-frag col)

      const unsigned short* qp = qkv + (rowbase + q) * 1536 + hh * 64;
      bf16x8 qf0 = *(const bf16x8*)(qp + fq * 8);
      bf16x8 qf1 = *(const bf16x8*)(qp + 32 + fq * 8);

      const unsigned short* Kb = lds + s * 8192;
      f32x4 sacc[4];
      #pragma unroll
      for (int mf = 0; mf < 4; ++mf) sacc[mf] = (f32x4){0.f, 0.f, 0.f, 0.f};
      #pragma unroll
      for (int mf = 0; mf < 4; ++mf) {
        bf16x8 k0 = *(const bf16x8*)(Kb + (mf * 16 + fr) * 64 + ((fq ^ (fr & 7)) << 3));
        bf16x8 k1 = *(const bf16x8*)(Kb + (mf * 16 + fr) * 64 + (((4 + fq) ^ (fr & 7)) << 3));
        sacc[mf] = mfma16(k0, qf0, sacc[mf]);
        sacc[mf] = mfma16(k1, qf1, sacc[mf]);
      }

      // lane-local masked softmax over 16 values + 2 shuffles across fq-group
      float ev[4][4];
      float vmx = -1e30f;
      #pragma unroll
      for (int mf = 0; mf < 4; ++mf)
        #pragma unroll
        for (int r = 0; r < 4; ++r) {
          int tk = t0 - BAND + mf * 16 + fq * 4 + r;
          bool ok = (tk >= q - BAND) && (tk <= q + BAND) && (tk >= 0) && (tk < T_);
          float v = ok ? sacc[mf][r] * 0.125f : -1e30f;
          ev[mf][r] = v;
          vmx = fmaxf(vmx, v);
        }
      vmx = fmaxf(vmx, __shfl_xor(vmx, 16, 64));
      vmx = fmaxf(vmx, __shfl_xor(vmx, 32, 64));
      float ssum = 0.f;
      #pragma unroll
      for (int mf = 0; mf < 4; ++mf)
        #pragma unroll
        for (int r = 0; r < 4; ++r) {
          float e = (ev[mf][r] > -1e29f) ? exp2f((ev[mf][r] - vmx) * 1.44269504f) : 0.f;
          ev[mf][r] = e;
          ssum += e;
        }
      ssum += __shfl_xor(ssum, 16, 64);
      ssum += __shfl_xor(ssum, 32, 64);
      float inv = 1.0f / ssum;

      // P (scaled) -> wave-private LDS [16 q-rows][stride 72]
      unsigned short* Pb = lds + 32768 + wave * 1152;
      #pragma unroll
      for (int mf = 0; mf < 4; ++mf)
        #pragma unroll
        for (int r = 0; r < 4; ++r)
          Pb[fr * 72 + mf * 16 + fq * 4 + r] = f2b(ev[mf][r] * inv);
      asm volatile("s_waitcnt lgkmcnt(0)" ::: "memory");
      __builtin_amdgcn_sched_barrier(0);

      // O = P V
      const unsigned short* Vb = lds + s * 8192 + 4096;
      f32x4 oacc[4];
      #pragma unroll
      for (int cf = 0; cf < 4; ++cf) oacc[cf] = (f32x4){0.f, 0.f, 0.f, 0.f};
      #pragma unroll
      for (int kk = 0; kk < 2; ++kk) {
        bf16x8 pa = *(const bf16x8*)(Pb + fr * 72 + (kk * 4 + fq) * 8);
        #pragma unroll
        for (int cf = 0; cf < 4; ++cf) {
          int du = cf * 2 + (fr >> 3);
          bf16x8 vf = *(const bf16x8*)(Vb + (cf * 16 + fr) * 64 + (((kk * 4 + fq) ^ du) << 3));
          oacc[cf] = mfma16(pa, vf, oacc[cf]);
        }
      }

      // O -> LDS tile [32][512], unit-swizzled by (q&7)
      #pragma unroll
      for (int cf = 0; cf < 4; ++cf)
        #pragma unroll
        for (int r = 0; r < 4; ++r) {
          int qq = qg * 16 + fq * 4 + r;
          int unit = hh * 8 + (((cf * 2 + (fr >> 3)) ^ (qq & 7)));
          Ob[qq * 512 + unit * 8 + (fr & 7)] = f2b(oacc[cf][r]);
        }
    }
    __syncthreads();
  }

  // ---- out-proj: C[32][512] = O @ woutb^T + bias + x, fp32 out ----
  // wave w owns cols [w*64, w*64+64)
  f32x4 acc[2][4];
  #pragma unroll
  for (int mf = 0; mf < 2; ++mf)
    #pragma unroll
    for (int nf = 0; nf < 4; ++nf) acc[mf][nf] = (f32x4){0.f, 0.f, 0.f, 0.f};

  const unsigned short* Bb = woutb + (size_t)(wave * 64) * 512;
  #pragma unroll 4
  for (int ks = 0; ks < 16; ++ks) {
    bf16x8 a0 = *(const bf16x8*)(Ob + (0 * 16 + fr) * 512 + (((ks * 4 + fq) ^ (fr & 7)) << 3));
    bf16x8 a1 = *(const bf16x8*)(Ob + (1 * 16 + fr) * 512 + (((ks * 4 + fq) ^ (fr & 7)) << 3));
    bf16x8 bfr[4];
    #pragma unroll
    for (int nf = 0; nf < 4; ++nf)
      bfr[nf] = *(const bf16x8*)(Bb + (size_t)(nf * 16 + fr) * 512 + ks * 32 + fq * 8);
    #pragma unroll
    for (int nf = 0; nf < 4; ++nf) {
      acc[0][nf] = mfma16(a0, bfr[nf], acc[0][nf]);
      acc[1][nf] = mfma16(a1, bfr[nf], acc[1][nf]);
    }
  }

  #pragma unroll
  for (int mf = 0; mf < 2; ++mf)
    #pragma unroll
    for (int nf = 0; nf < 4; ++nf) {
      int col = wave * 64 + nf * 16 + fr;
      float bv = bout[col];
      #pragma unroll
      for (int r = 0; r < 4; ++r) {
        size_t e = (size_t)(r0g + mf * 16 + fq * 4 + r) * 512 + col;
        out[e] = x[e] + acc[mf][nf][r] + bv;
      }
    }
}

extern "C" void kernel_launch(void* const* d_in, const int* in_sizes, int n_in,
                              void* d_out, int out_size, void* d_ws, size_t ws_size,
                              hipStream_t stream) {
  (void)in_sizes; (void)n_in; (void)out_size; (void)ws_size;
  const float* x     = (const float*)d_in[0];
  const float* ln_g  = (const float*)d_in[1];
  const float* ln_b  = (const float*)d_in[2];
  const float* w_in  = (const float*)d_in[3];
  const float* b_in  = (const float*)d_in[4];
  const float* w_out = (const float*)d_in[5];
  const float* b_out = (const float*)d_in[6];
  float* out = (float*)d_out;

  char* ws = (char*)d_ws;
  unsigned short* hb    = (unsigned short*)(ws);              // 8192*512   bf16
  unsigned short* winb  = (unsigned short*)(ws + 8388608);    // 1536*512   bf16
  unsigned short* woutb = (unsigned short*)(ws + 9961472);    // 512*512    bf16
  unsigned short* qkvb  = (unsigned short*)(ws + 10485760);   // 8192*1536  bf16

  (void)hipFuncSetAttribute((const void*)gemm_qkv8,
                            hipFuncAttributeMaxDynamicSharedMemorySize, 131072);
  (void)hipFuncSetAttribute((const void*)attn_out_k,
                            hipFuncAttributeMaxDynamicSharedMemorySize, 116736);

  prep_k<<<3072, 256, 0, stream>>>(x, ln_g, ln_b, w_in, w_out, hb, winb, woutb);
  gemm_qkv8<<<192, 512, 131072, stream>>>(hb, winb, b_in, qkvb);
  attn_out_k<<<256, 512, 116736, stream>>>(qkvb, woutb, b_out, x, out);
}